// Round 18
// baseline (345.808 us; speedup 1.0000x reference)
//
#include <hip/hip_runtime.h>

typedef _Float16 half8 __attribute__((ext_vector_type(8)));
typedef _Float16 half4 __attribute__((ext_vector_type(4)));
typedef float f32x4 __attribute__((ext_vector_type(4)));

__device__ __forceinline__ void lds_load16(const void* g, void* l) {
  __builtin_amdgcn_global_load_lds((const __attribute__((address_space(1))) void*)g,
                                   (__attribute__((address_space(3))) void*)l, 16, 0, 0);
}

__device__ __forceinline__ void lds_barrier() {
  asm volatile("s_waitcnt lgkmcnt(0)" ::: "memory");
  asm volatile("s_barrier" ::: "memory");
}

// ------- fused converts (R16) -------
__global__ __launch_bounds__(256) void cvt_all(const float* __restrict__ X,
                                               const float* __restrict__ Wq, const float* __restrict__ Wk,
                                               const float* __restrict__ Wv, const float* __restrict__ Wo,
                                               _Float16* __restrict__ Xh,
                                               _Float16* __restrict__ Wqkvt, _Float16* __restrict__ Wot) {
  const int bid = blockIdx.x, tid = threadIdx.x;
  if (bid < 6144) {
    int i = bid * 256 + tid;
    const float4* p = (const float4*)(X + (size_t)i * 8);
    float4 a = p[0], b = p[1];
    half8 v;
    v[0] = (_Float16)a.x; v[1] = (_Float16)a.y; v[2] = (_Float16)a.z; v[3] = (_Float16)a.w;
    v[4] = (_Float16)b.x; v[5] = (_Float16)b.y; v[6] = (_Float16)b.z; v[7] = (_Float16)b.w;
    *(half8*)(Xh + (size_t)i * 8) = v;
  } else {
    __shared__ _Float16 T[64][72];
    const int t = bid - 6144;
    const int part = t / 144;
    const int r = t - part * 144;
    const int k0 = (r / 12) * 64, n0 = (r - (r / 12) * 12) * 64;
    const float* W = part == 0 ? Wq : part == 1 ? Wk : part == 2 ? Wv : Wo;
    const int lr0 = tid >> 4, lc0 = (tid & 15) * 4;
#pragma unroll
    for (int rr = 0; rr < 4; ++rr) {
      const int row = lr0 + rr * 16;
      float4 v = *(const float4*)(W + (size_t)(k0 + row) * 768 + n0 + lc0);
      T[lc0 + 0][row] = (_Float16)v.x;
      T[lc0 + 1][row] = (_Float16)v.y;
      T[lc0 + 2][row] = (_Float16)v.z;
      T[lc0 + 3][row] = (_Float16)v.w;
    }
    __syncthreads();
    _Float16* Wt = part < 3 ? (Wqkvt + (size_t)(part * 768 + n0) * 768 + k0)
                            : (Wot + (size_t)n0 * 768 + k0);
    const int wr0 = tid >> 4, wc0 = (tid & 15) * 4;
#pragma unroll
    for (int rr = 0; rr < 4; ++rr) {
      const int nrow = wr0 + rr * 16;
      half4 h = *(const half4*)&T[nrow][wc0];
      *(half4*)(Wt + (size_t)nrow * 768 + wc0) = h;
    }
  }
}

// ---------------- fp16 MFMA GEMM: 128x128, BK=32, 4 waves, 4 blocks/CU ----------------
// EPI=0: NEW epilogue — fp16 tile (bias folded) staged into the dead 32KB LDS
// (XOR-swizzled granules), then streamed as 32x1KB contiguous NT wave-stores
// matching the frag-major Q/K/V layouts (V staged transposed).
template <int EPI, int NB>
__global__ __launch_bounds__(256, 4) void gemm128(
    const _Float16* __restrict__ A, const _Float16* __restrict__ Bt,
    const float* __restrict__ b0, const float* __restrict__ b1, const float* __restrict__ b2,
    _Float16* __restrict__ Qo, _Float16* __restrict__ Ko, _Float16* __restrict__ Vto,
    float* __restrict__ Co) {
  __shared__ _Float16 LB[16384];           // 32KB: gemm dbuf, then epilogue tile
  _Float16* Ab = LB;                        // [2][4096]
  _Float16* Bb = LB + 8192;                 // [2][4096]
  const int tid = threadIdx.x, w = tid >> 6, l = tid & 63;
  const int lr = l & 15, lk = l >> 4;
  const int wm = w >> 1, wn = w & 1;
  const int q8 = (int)gridDim.x >> 3;
  const int wg = ((int)blockIdx.x & 7) * q8 + ((int)blockIdx.x >> 3);
  const int m0 = (wg / NB) * 128, n0 = (wg % NB) * 128;

  auto STAGE = [&](int kt, int dstb) {
#pragma unroll
    for (int i = 0; i < 2; ++i) {
      const int g = i * 256 + tid;
      const int row = g >> 2;
      const int gr = (g & 3) ^ (row & 3);
      lds_load16(A + (size_t)(m0 + row) * 768 + kt * 32 + gr * 8,
                 (char*)(Ab + dstb * 4096) + g * 16);
      lds_load16(Bt + (size_t)(n0 + row) * 768 + kt * 32 + gr * 8,
                 (char*)(Bb + dstb * 4096) + g * 16);
    }
  };

  f32x4 acc[4][4] = {};
  STAGE(0, 0);
  const int swzg = ((lk ^ (lr & 3)) * 8);

  for (int T = 0; T < 24; ++T) {
    const int b = T & 1;
    asm volatile("s_waitcnt vmcnt(0)" ::: "memory");
    asm volatile("s_barrier" ::: "memory");
    if (T < 23) STAGE(T + 1, b ^ 1);
    half8 af[4], bf[4];
#pragma unroll
    for (int mi = 0; mi < 4; ++mi)
      af[mi] = *(const half8*)&Ab[b * 4096 + (wm * 64 + mi * 16 + lr) * 32 + swzg];
#pragma unroll
    for (int ni = 0; ni < 4; ++ni)
      bf[ni] = *(const half8*)&Bb[b * 4096 + (wn * 64 + ni * 16 + lr) * 32 + swzg];
    __builtin_amdgcn_s_setprio(1);
#pragma unroll
    for (int mi = 0; mi < 4; ++mi)
#pragma unroll
      for (int ni = 0; ni < 4; ++ni)
        acc[mi][ni] = __builtin_amdgcn_mfma_f32_16x16x32_f16(af[mi], bf[ni], acc[mi][ni], 0, 0, 0);
    __builtin_amdgcn_s_setprio(0);
  }

  if (EPI == 0) {
    const int part = n0 / 768;               // uniform per block (768 = 6*128)
    const int e0 = n0 - part * 768;
    const float* bb = part == 0 ? b0 : part == 1 ? b1 : b2;
    const int bI = m0 >> 10, s0 = m0 & 1023;
    lds_barrier();                           // all waves done reading Ab/Bb
    // ---- stage fp16 tile into LB (Q/K: [row][col]; V: transposed [col][row]) ----
#pragma unroll
    for (int mi = 0; mi < 4; ++mi)
#pragma unroll
      for (int ni = 0; ni < 4; ++ni) {
        const int c = wn * 64 + ni * 16 + lr;
        const float bv = bb[e0 + c];
#pragma unroll
        for (int j = 0; j < 4; ++j) {
          const int r = wm * 64 + mi * 16 + lk * 4 + j;
          const _Float16 v = (_Float16)(acc[mi][ni][j] + bv);
          int a;
          if (part < 2) a = ((((r * 16 + (c >> 3)) ^ (r & 7)) << 3) | (c & 7));
          else          a = ((((c * 16 + (r >> 3)) ^ (c & 7)) << 3) | (r & 7));
          LB[a] = v;
        }
      }
    lds_barrier();
    // ---- stream 32 x 1KB contiguous chunks (8 per wave) ----
#pragma unroll
    for (int i = 0; i < 8; ++i) {
      const int chunk = w * 8 + i;
      if (part < 2) {
        const int st = chunk >> 2, ci = chunk & 3;
        const int g = ((st * 16 + (l & 15)) * 16 + ci * 4 + (l >> 4)) ^ (l & 7);
        half8 v = *(const half8*)&LB[g << 3];
        const int col0 = e0 + ci * 32;
        const int h = col0 / 96, kkv = (col0 - h * 96) >> 5;
        const size_t gb = ((((size_t)((bI * 8 + h) * 64 + (s0 >> 4) + st)) * 3 + kkv) << 9) + l * 8;
        __builtin_nontemporal_store(v, (half8*)((part == 0 ? Qo : Ko) + gb));
      } else {
        const int dc = chunk >> 2, kc = chunk & 3;
        const int g = ((dc * 16 + (l & 15)) * 16 + kc * 4 + (l >> 4)) ^ (l & 7);
        half8 v = *(const half8*)&LB[g << 3];
        const int col0 = e0 + dc * 16;
        const int h = col0 / 96, dtv = (col0 - h * 96) >> 4;
        const size_t gb = ((((size_t)((bI * 8 + h) * 6 + dtv)) * 32 + (s0 >> 5) + kc) << 9) + l * 8;
        __builtin_nontemporal_store(v, (half8*)(Vto + gb));
      }
    }
  } else {
#pragma unroll
    for (int mi = 0; mi < 4; ++mi) {
      const int rbase = m0 + wm * 64 + mi * 16 + lk * 4;
#pragma unroll
      for (int ni = 0; ni < 4; ++ni) {
        const int col = n0 + wn * 64 + ni * 16 + lr;
        const float bv = b0[col];
#pragma unroll
        for (int j = 0; j < 4; ++j) {
          const int row = rbase + j;
          __builtin_nontemporal_store(acc[mi][ni][j] + bv, Co + (size_t)row * 768 + col);
        }
      }
    }
  }
}

// ---------------- fused attention v11 (R14/R16, best known — FROZEN) ----------------
__global__ __launch_bounds__(512, 2) void attn(const _Float16* __restrict__ swzQ,
                                               const _Float16* __restrict__ swzK,
                                               const _Float16* __restrict__ swzV,
                                               float* __restrict__ probs,
                                               _Float16* __restrict__ ctx) {
  __shared__ __align__(16) float Pf[8][16][132];
  __shared__ float lsb[8][2][16];
  const int tid = threadIdx.x, w = tid >> 6, l = tid & 63;
  const int lr = l & 15, lk = l >> 4;
  const int id = blockIdx.x;
  const int lid = (id & 7) * 512 + (id >> 3);
  const int bh = lid >> 5, qt2 = lid & 31;
  const int q0 = qt2 * 32;
  const float SC = 0.10206207261596577f * 1.4426950408889634f;
  const int b = bh >> 3, h = bh & 7;

  const half8* qbA = (const half8*)swzQ + (size_t)(bh * 64 + qt2 * 2) * 192;
  const half8* kb  = (const half8*)swzK + (size_t)(bh * 64 + w * 8) * 192;
  const half8* vb0 = (const half8*)swzV + (size_t)bh * 12288;
  half8 bqA[3], bqB[3];
#pragma unroll
  for (int kk = 0; kk < 3; ++kk) { bqA[kk] = qbA[kk * 64 + l]; bqB[kk] = qbA[192 + kk * 64 + l]; }
  half8 kf[8][3];
#pragma unroll
  for (int ct = 0; ct < 8; ++ct)
#pragma unroll
    for (int kk = 0; kk < 3; ++kk) kf[ct][kk] = kb[(ct * 3 + kk) * 64 + l];

  f32x4 sA[8], sB[8];
#pragma unroll
  for (int ct = 0; ct < 8; ++ct) {
    f32x4 aA = {0.f, 0.f, 0.f, 0.f}, aB = {0.f, 0.f, 0.f, 0.f};
#pragma unroll
    for (int kk = 0; kk < 3; ++kk) {
      aA = __builtin_amdgcn_mfma_f32_16x16x32_f16(kf[ct][kk], bqA[kk], aA, 0, 0, 0);
      aB = __builtin_amdgcn_mfma_f32_16x16x32_f16(kf[ct][kk], bqB[kk], aB, 0, 0, 0);
    }
    sA[ct] = aA; sB[ct] = aB;
  }

  float psA = 0.f, psB = 0.f;
#pragma unroll
  for (int ct = 0; ct < 8; ++ct)
#pragma unroll
    for (int j = 0; j < 4; ++j) {
      const float eA = __builtin_amdgcn_exp2f(sA[ct][j] * SC);
      const float eB = __builtin_amdgcn_exp2f(sB[ct][j] * SC);
      sA[ct][j] = eA; psA += eA;
      sB[ct][j] = eB; psB += eB;
    }
  psA += __shfl_xor(psA, 16); psA += __shfl_xor(psA, 32);
  psB += __shfl_xor(psB, 16); psB += __shfl_xor(psB, 32);
  if (lk == 0) { lsb[w][0][lr] = psA; lsb[w][1][lr] = psB; }

  half8 vf[6][4];
#pragma unroll
  for (int dt = 0; dt < 6; ++dt)
#pragma unroll
    for (int kk = 0; kk < 4; ++kk) vf[dt][kk] = vb0[(dt * 32 + w * 4 + kk) * 64 + l];

  lds_barrier();                                     // B1
  float ltA = 0.f, ltB = 0.f;
#pragma unroll
  for (int ww = 0; ww < 8; ++ww) { ltA += lsb[ww][0][lr]; ltB += lsb[ww][1][lr]; }
  const float invlA = 1.f / ltA, invlB = 1.f / ltB;

  const int qh = l >> 5, c4 = (l & 31) * 4;
  float* cbw = (float*)&Pf[w][0][0];
  const int rq = tid >> 5;
  const int rd0 = (tid & 31) * 3;

  // ---- phase A ----
#pragma unroll
  for (int ct = 0; ct < 8; ++ct) {
    f32x4 p4;
#pragma unroll
    for (int j = 0; j < 4; ++j) p4[j] = sA[ct][j] * invlA;
    *(f32x4*)&Pf[w][lr][ct * 16 + lk * 4] = p4;
  }
  {
    float* pbase = probs + ((size_t)bh << 20) + (size_t)q0 * 1024 + w * 128;
#pragma unroll
    for (int r2 = 0; r2 < 8; ++r2) {
      const int q = r2 * 2 + qh;
      f32x4 v = *(const f32x4*)&Pf[w][q][c4];
      __builtin_nontemporal_store(v, (f32x4*)(pbase + (size_t)q * 1024 + c4));
    }
  }
  f32x4 cacc[6] = {};
#pragma unroll
  for (int kk = 0; kk < 4; ++kk) {
    f32x4 a0 = *(const f32x4*)&Pf[w][lr][kk * 32 + lk * 8];
    f32x4 a1 = *(const f32x4*)&Pf[w][lr][kk * 32 + lk * 8 + 4];
    half8 pa;
#pragma unroll
    for (int e = 0; e < 4; ++e) { pa[e] = (_Float16)a0[e]; pa[4 + e] = (_Float16)a1[e]; }
#pragma unroll
    for (int dt = 0; dt < 6; ++dt)
      cacc[dt] = __builtin_amdgcn_mfma_f32_16x16x32_f16(pa, vf[dt][kk], cacc[dt], 0, 0, 0);
  }
#pragma unroll
  for (int dt = 0; dt < 6; ++dt)
#pragma unroll
    for (int j = 0; j < 4; ++j)
      cbw[(lk * 4 + j) * 100 + dt * 16 + lr] = cacc[dt][j];
  lds_barrier();                                     // B2
  {
    _Float16* cg = ctx + ((size_t)(b * 1024 + q0 + rq)) * 768 + h * 96 + rd0;
#pragma unroll
    for (int e = 0; e < 3; ++e) {
      float v = 0.f;
#pragma unroll
      for (int ww = 0; ww < 8; ++ww) v += ((const float*)&Pf[ww][0][0])[rq * 100 + rd0 + e];
      cg[e] = (_Float16)v;
    }
  }
  lds_barrier();                                     // B3

  // ---- phase B ----
#pragma unroll
  for (int ct = 0; ct < 8; ++ct) {
    f32x4 p4;
#pragma unroll
    for (int j = 0; j < 4; ++j) p4[j] = sB[ct][j] * invlB;
    *(f32x4*)&Pf[w][lr][ct * 16 + lk * 4] = p4;
  }
  {
    float* pbase = probs + ((size_t)bh << 20) + (size_t)(q0 + 16) * 1024 + w * 128;
#pragma unroll
    for (int r2 = 0; r2 < 8; ++r2) {
      const int q = r2 * 2 + qh;
      f32x4 v = *(const f32x4*)&Pf[w][q][c4];
      __builtin_nontemporal_store(v, (f32x4*)(pbase + (size_t)q * 1024 + c4));
    }
  }
#pragma unroll
  for (int dt = 0; dt < 6; ++dt) cacc[dt] = f32x4{0.f, 0.f, 0.f, 0.f};
#pragma unroll
  for (int kk = 0; kk < 4; ++kk) {
    f32x4 a0 = *(const f32x4*)&Pf[w][lr][kk * 32 + lk * 8];
    f32x4 a1 = *(const f32x4*)&Pf[w][lr][kk * 32 + lk * 8 + 4];
    half8 pa;
#pragma unroll
    for (int e = 0; e < 4; ++e) { pa[e] = (_Float16)a0[e]; pa[4 + e] = (_Float16)a1[e]; }
#pragma unroll
    for (int dt = 0; dt < 6; ++dt)
      cacc[dt] = __builtin_amdgcn_mfma_f32_16x16x32_f16(pa, vf[dt][kk], cacc[dt], 0, 0, 0);
  }
#pragma unroll
  for (int dt = 0; dt < 6; ++dt)
#pragma unroll
    for (int j = 0; j < 4; ++j)
      cbw[(lk * 4 + j) * 100 + dt * 16 + lr] = cacc[dt][j];
  lds_barrier();                                     // B4
  {
    _Float16* cg = ctx + ((size_t)(b * 1024 + q0 + 16 + rq)) * 768 + h * 96 + rd0;
#pragma unroll
    for (int e = 0; e < 3; ++e) {
      float v = 0.f;
#pragma unroll
      for (int ww = 0; ww < 8; ++ww) v += ((const float*)&Pf[ww][0][0])[rq * 100 + rd0 + e];
      cg[e] = (_Float16)v;
    }
  }
}

extern "C" void kernel_launch(void* const* d_in, const int* in_sizes, int n_in,
                              void* d_out, int out_size, void* d_ws, size_t ws_size,
                              hipStream_t stream) {
  (void)in_sizes; (void)n_in; (void)out_size; (void)ws_size;
  const float* X  = (const float*)d_in[0];
  const float* Wq = (const float*)d_in[1];
  const float* bq = (const float*)d_in[2];
  const float* Wk = (const float*)d_in[3];
  const float* bk = (const float*)d_in[4];
  const float* Wv = (const float*)d_in[5];
  const float* bv = (const float*)d_in[6];
  const float* Wo = (const float*)d_in[7];
  const float* bo = (const float*)d_in[8];

  char* ws = (char*)d_ws;
  _Float16* Xh    = (_Float16*)(ws + 0);          // 16384x768 fp16      (25165824 B)
  _Float16* Wqkvt = (_Float16*)(ws + 25165824);   // 2304x768 fp16       ( 3538944 B)
  _Float16* Wot   = (_Float16*)(ws + 28704768);   // 768x768 fp16        ( 1179648 B)
  _Float16* Qh    = (_Float16*)(ws + 29884416);   // swzQ                (25165824 B)
  _Float16* Kh    = (_Float16*)(ws + 55050240);   // swzK                (25165824 B)
  _Float16* Vth   = (_Float16*)(ws + 80216064);   // swzV                (25165824 B)
  _Float16* Ctx   = (_Float16*)(ws + 105381888);  // [16384][768]        (25165824 B)

  float* out   = (float*)d_out;
  float* probs = out + 12582912;                  // [16][8][1024][1024]

  cvt_all<<<dim3(6720), dim3(256), 0, stream>>>(X, Wq, Wk, Wv, Wo, Xh, Wqkvt, Wot);
  gemm128<0, 18><<<dim3(2304), dim3(256), 0, stream>>>(Xh, Wqkvt, bq, bk, bv, Qh, Kh, Vth, nullptr);
  attn<<<dim3(4096), dim3(512), 0, stream>>>(Qh, Kh, Vth, probs, Ctx);
  gemm128<1, 6><<<dim3(768), dim3(256), 0, stream>>>(Ctx, Wot, bo, bo, bo, nullptr, nullptr, nullptr, out);
}

// Round 19
// 297.913 us; speedup vs baseline: 1.1608x; 1.1608x over previous
//
#include <hip/hip_runtime.h>

typedef _Float16 half8 __attribute__((ext_vector_type(8)));
typedef _Float16 half4 __attribute__((ext_vector_type(4)));
typedef float f32x4 __attribute__((ext_vector_type(4)));

__device__ __forceinline__ void lds_load16(const void* g, void* l) {
  __builtin_amdgcn_global_load_lds((const __attribute__((address_space(1))) void*)g,
                                   (__attribute__((address_space(3))) void*)l, 16, 0, 0);
}

__device__ __forceinline__ void lds_barrier() {
  asm volatile("s_waitcnt lgkmcnt(0)" ::: "memory");
  asm volatile("s_barrier" ::: "memory");
}

// ------- fused converts (R16) -------
__global__ __launch_bounds__(256) void cvt_all(const float* __restrict__ X,
                                               const float* __restrict__ Wq, const float* __restrict__ Wk,
                                               const float* __restrict__ Wv, const float* __restrict__ Wo,
                                               _Float16* __restrict__ Xh,
                                               _Float16* __restrict__ Wqkvt, _Float16* __restrict__ Wot) {
  const int bid = blockIdx.x, tid = threadIdx.x;
  if (bid < 6144) {
    int i = bid * 256 + tid;
    const float4* p = (const float4*)(X + (size_t)i * 8);
    float4 a = p[0], b = p[1];
    half8 v;
    v[0] = (_Float16)a.x; v[1] = (_Float16)a.y; v[2] = (_Float16)a.z; v[3] = (_Float16)a.w;
    v[4] = (_Float16)b.x; v[5] = (_Float16)b.y; v[6] = (_Float16)b.z; v[7] = (_Float16)b.w;
    *(half8*)(Xh + (size_t)i * 8) = v;
  } else {
    __shared__ _Float16 T[64][72];
    const int t = bid - 6144;
    const int part = t / 144;
    const int r = t - part * 144;
    const int k0 = (r / 12) * 64, n0 = (r - (r / 12) * 12) * 64;
    const float* W = part == 0 ? Wq : part == 1 ? Wk : part == 2 ? Wv : Wo;
    const int lr0 = tid >> 4, lc0 = (tid & 15) * 4;
#pragma unroll
    for (int rr = 0; rr < 4; ++rr) {
      const int row = lr0 + rr * 16;
      float4 v = *(const float4*)(W + (size_t)(k0 + row) * 768 + n0 + lc0);
      T[lc0 + 0][row] = (_Float16)v.x;
      T[lc0 + 1][row] = (_Float16)v.y;
      T[lc0 + 2][row] = (_Float16)v.z;
      T[lc0 + 3][row] = (_Float16)v.w;
    }
    __syncthreads();
    _Float16* Wt = part < 3 ? (Wqkvt + (size_t)(part * 768 + n0) * 768 + k0)
                            : (Wot + (size_t)n0 * 768 + k0);
    const int wr0 = tid >> 4, wc0 = (tid & 15) * 4;
#pragma unroll
    for (int rr = 0; rr < 4; ++rr) {
      const int nrow = wr0 + rr * 16;
      half4 h = *(const half4*)&T[nrow][wc0];
      *(half4*)(Wt + (size_t)nrow * 768 + wc0) = h;
    }
  }
}

// ---------------- fp16 MFMA GEMM: 128x128, BK=32, 4 waves, 4 blocks/CU (R11/R16) ----------------
template <int EPI, int NB>
__global__ __launch_bounds__(256, 4) void gemm128(
    const _Float16* __restrict__ A, const _Float16* __restrict__ Bt,
    const float* __restrict__ b0, const float* __restrict__ b1, const float* __restrict__ b2,
    _Float16* __restrict__ Qo, _Float16* __restrict__ Ko, _Float16* __restrict__ Vto,
    float* __restrict__ Co) {
  __shared__ _Float16 Ab[2][128 * 32];
  __shared__ _Float16 Bb[2][128 * 32];
  const int tid = threadIdx.x, w = tid >> 6, l = tid & 63;
  const int lr = l & 15, lk = l >> 4;
  const int wm = w >> 1, wn = w & 1;
  const int q8 = (int)gridDim.x >> 3;
  const int wg = ((int)blockIdx.x & 7) * q8 + ((int)blockIdx.x >> 3);
  const int m0 = (wg / NB) * 128, n0 = (wg % NB) * 128;

  auto STAGE = [&](int kt, int dstb) {
#pragma unroll
    for (int i = 0; i < 2; ++i) {
      const int g = i * 256 + tid;
      const int row = g >> 2;
      const int gr = (g & 3) ^ (row & 3);
      lds_load16(A + (size_t)(m0 + row) * 768 + kt * 32 + gr * 8,
                 (char*)&Ab[dstb][0] + g * 16);
      lds_load16(Bt + (size_t)(n0 + row) * 768 + kt * 32 + gr * 8,
                 (char*)&Bb[dstb][0] + g * 16);
    }
  };

  f32x4 acc[4][4] = {};
  STAGE(0, 0);
  const int swzg = ((lk ^ (lr & 3)) * 8);

  for (int T = 0; T < 24; ++T) {
    const int b = T & 1;
    asm volatile("s_waitcnt vmcnt(0)" ::: "memory");
    asm volatile("s_barrier" ::: "memory");
    if (T < 23) STAGE(T + 1, b ^ 1);
    half8 af[4], bf[4];
#pragma unroll
    for (int mi = 0; mi < 4; ++mi)
      af[mi] = *(const half8*)&Ab[b][(wm * 64 + mi * 16 + lr) * 32 + swzg];
#pragma unroll
    for (int ni = 0; ni < 4; ++ni)
      bf[ni] = *(const half8*)&Bb[b][(wn * 64 + ni * 16 + lr) * 32 + swzg];
    __builtin_amdgcn_s_setprio(1);
#pragma unroll
    for (int mi = 0; mi < 4; ++mi)
#pragma unroll
      for (int ni = 0; ni < 4; ++ni)
        acc[mi][ni] = __builtin_amdgcn_mfma_f32_16x16x32_f16(af[mi], bf[ni], acc[mi][ni], 0, 0, 0);
    __builtin_amdgcn_s_setprio(0);
  }

#pragma unroll
  for (int mi = 0; mi < 4; ++mi) {
    const int rbase = m0 + wm * 64 + mi * 16 + lk * 4;
#pragma unroll
    for (int ni = 0; ni < 4; ++ni) {
      const int col = n0 + wn * 64 + ni * 16 + lr;
      if (EPI == 0) {
        const int part = col / 768;
        const int e = col - part * 768;
        const int h = e / 96, d = e - (e / 96) * 96;
        const float* bb = part == 0 ? b0 : part == 1 ? b1 : b2;
        const float bv = bb[e];
#pragma unroll
        for (int j = 0; j < 4; ++j) {
          const int row = rbase + j;
          const int bI = row >> 10, s = row & 1023;
          const int bh = bI * 8 + h;
          const _Float16 v = (_Float16)(acc[mi][ni][j] + bv);
          if (part < 2) {
            const size_t idx = ((((size_t)(bh * 64 + (s >> 4)) * 3 + (d >> 5)) * 64
                                + ((d & 31) >> 3) * 16 + (s & 15)) << 3) + (d & 7);
            if (part == 0) Qo[idx] = v; else Ko[idx] = v;
          } else {
            const size_t idx = ((((size_t)(bh * 6 + (d >> 4)) * 32 + (s >> 5)) * 64
                                + ((s & 31) >> 3) * 16 + (d & 15)) << 3) + (s & 7);
            Vto[idx] = v;
          }
        }
      } else {
        const float bv = b0[col];
#pragma unroll
        for (int j = 0; j < 4; ++j) {
          const int row = rbase + j;
          __builtin_nontemporal_store(acc[mi][ni][j] + bv, Co + (size_t)row * 768 + col);
        }
      }
    }
  }
}

// ---------------- fused attention v11 (R14/R16, best known — FROZEN) ----------------
__global__ __launch_bounds__(512, 2) void attn(const _Float16* __restrict__ swzQ,
                                               const _Float16* __restrict__ swzK,
                                               const _Float16* __restrict__ swzV,
                                               float* __restrict__ probs,
                                               _Float16* __restrict__ ctx) {
  __shared__ __align__(16) float Pf[8][16][132];
  __shared__ float lsb[8][2][16];
  const int tid = threadIdx.x, w = tid >> 6, l = tid & 63;
  const int lr = l & 15, lk = l >> 4;
  const int id = blockIdx.x;
  const int lid = (id & 7) * 512 + (id >> 3);
  const int bh = lid >> 5, qt2 = lid & 31;
  const int q0 = qt2 * 32;
  const float SC = 0.10206207261596577f * 1.4426950408889634f;
  const int b = bh >> 3, h = bh & 7;

  const half8* qbA = (const half8*)swzQ + (size_t)(bh * 64 + qt2 * 2) * 192;
  const half8* kb  = (const half8*)swzK + (size_t)(bh * 64 + w * 8) * 192;
  const half8* vb0 = (const half8*)swzV + (size_t)bh * 12288;
  half8 bqA[3], bqB[3];
#pragma unroll
  for (int kk = 0; kk < 3; ++kk) { bqA[kk] = qbA[kk * 64 + l]; bqB[kk] = qbA[192 + kk * 64 + l]; }
  half8 kf[8][3];
#pragma unroll
  for (int ct = 0; ct < 8; ++ct)
#pragma unroll
    for (int kk = 0; kk < 3; ++kk) kf[ct][kk] = kb[(ct * 3 + kk) * 64 + l];

  f32x4 sA[8], sB[8];
#pragma unroll
  for (int ct = 0; ct < 8; ++ct) {
    f32x4 aA = {0.f, 0.f, 0.f, 0.f}, aB = {0.f, 0.f, 0.f, 0.f};
#pragma unroll
    for (int kk = 0; kk < 3; ++kk) {
      aA = __builtin_amdgcn_mfma_f32_16x16x32_f16(kf[ct][kk], bqA[kk], aA, 0, 0, 0);
      aB = __builtin_amdgcn_mfma_f32_16x16x32_f16(kf[ct][kk], bqB[kk], aB, 0, 0, 0);
    }
    sA[ct] = aA; sB[ct] = aB;
  }

  float psA = 0.f, psB = 0.f;
#pragma unroll
  for (int ct = 0; ct < 8; ++ct)
#pragma unroll
    for (int j = 0; j < 4; ++j) {
      const float eA = __builtin_amdgcn_exp2f(sA[ct][j] * SC);
      const float eB = __builtin_amdgcn_exp2f(sB[ct][j] * SC);
      sA[ct][j] = eA; psA += eA;
      sB[ct][j] = eB; psB += eB;
    }
  psA += __shfl_xor(psA, 16); psA += __shfl_xor(psA, 32);
  psB += __shfl_xor(psB, 16); psB += __shfl_xor(psB, 32);
  if (lk == 0) { lsb[w][0][lr] = psA; lsb[w][1][lr] = psB; }

  half8 vf[6][4];
#pragma unroll
  for (int dt = 0; dt < 6; ++dt)
#pragma unroll
    for (int kk = 0; kk < 4; ++kk) vf[dt][kk] = vb0[(dt * 32 + w * 4 + kk) * 64 + l];

  lds_barrier();                                     // B1
  float ltA = 0.f, ltB = 0.f;
#pragma unroll
  for (int ww = 0; ww < 8; ++ww) { ltA += lsb[ww][0][lr]; ltB += lsb[ww][1][lr]; }
  const float invlA = 1.f / ltA, invlB = 1.f / ltB;

  const int qh = l >> 5, c4 = (l & 31) * 4;
  float* cbw = (float*)&Pf[w][0][0];
  const int rq = tid >> 5;
  const int rd0 = (tid & 31) * 3;

  // ---- phase A ----
#pragma unroll
  for (int ct = 0; ct < 8; ++ct) {
    f32x4 p4;
#pragma unroll
    for (int j = 0; j < 4; ++j) p4[j] = sA[ct][j] * invlA;
    *(f32x4*)&Pf[w][lr][ct * 16 + lk * 4] = p4;
  }
  {
    float* pbase = probs + ((size_t)bh << 20) + (size_t)q0 * 1024 + w * 128;
#pragma unroll
    for (int r2 = 0; r2 < 8; ++r2) {
      const int q = r2 * 2 + qh;
      f32x4 v = *(const f32x4*)&Pf[w][q][c4];
      __builtin_nontemporal_store(v, (f32x4*)(pbase + (size_t)q * 1024 + c4));
    }
  }
  f32x4 cacc[6] = {};
#pragma unroll
  for (int kk = 0; kk < 4; ++kk) {
    f32x4 a0 = *(const f32x4*)&Pf[w][lr][kk * 32 + lk * 8];
    f32x4 a1 = *(const f32x4*)&Pf[w][lr][kk * 32 + lk * 8 + 4];
    half8 pa;
#pragma unroll
    for (int e = 0; e < 4; ++e) { pa[e] = (_Float16)a0[e]; pa[4 + e] = (_Float16)a1[e]; }
#pragma unroll
    for (int dt = 0; dt < 6; ++dt)
      cacc[dt] = __builtin_amdgcn_mfma_f32_16x16x32_f16(pa, vf[dt][kk], cacc[dt], 0, 0, 0);
  }
#pragma unroll
  for (int dt = 0; dt < 6; ++dt)
#pragma unroll
    for (int j = 0; j < 4; ++j)
      cbw[(lk * 4 + j) * 100 + dt * 16 + lr] = cacc[dt][j];
  lds_barrier();                                     // B2
  {
    _Float16* cg = ctx + ((size_t)(b * 1024 + q0 + rq)) * 768 + h * 96 + rd0;
#pragma unroll
    for (int e = 0; e < 3; ++e) {
      float v = 0.f;
#pragma unroll
      for (int ww = 0; ww < 8; ++ww) v += ((const float*)&Pf[ww][0][0])[rq * 100 + rd0 + e];
      cg[e] = (_Float16)v;
    }
  }
  lds_barrier();                                     // B3

  // ---- phase B ----
#pragma unroll
  for (int ct = 0; ct < 8; ++ct) {
    f32x4 p4;
#pragma unroll
    for (int j = 0; j < 4; ++j) p4[j] = sB[ct][j] * invlB;
    *(f32x4*)&Pf[w][lr][ct * 16 + lk * 4] = p4;
  }
  {
    float* pbase = probs + ((size_t)bh << 20) + (size_t)(q0 + 16) * 1024 + w * 128;
#pragma unroll
    for (int r2 = 0; r2 < 8; ++r2) {
      const int q = r2 * 2 + qh;
      f32x4 v = *(const f32x4*)&Pf[w][q][c4];
      __builtin_nontemporal_store(v, (f32x4*)(pbase + (size_t)q * 1024 + c4));
    }
  }
#pragma unroll
  for (int dt = 0; dt < 6; ++dt) cacc[dt] = f32x4{0.f, 0.f, 0.f, 0.f};
#pragma unroll
  for (int kk = 0; kk < 4; ++kk) {
    f32x4 a0 = *(const f32x4*)&Pf[w][lr][kk * 32 + lk * 8];
    f32x4 a1 = *(const f32x4*)&Pf[w][lr][kk * 32 + lk * 8 + 4];
    half8 pa;
#pragma unroll
    for (int e = 0; e < 4; ++e) { pa[e] = (_Float16)a0[e]; pa[4 + e] = (_Float16)a1[e]; }
#pragma unroll
    for (int dt = 0; dt < 6; ++dt)
      cacc[dt] = __builtin_amdgcn_mfma_f32_16x16x32_f16(pa, vf[dt][kk], cacc[dt], 0, 0, 0);
  }
#pragma unroll
  for (int dt = 0; dt < 6; ++dt)
#pragma unroll
    for (int j = 0; j < 4; ++j)
      cbw[(lk * 4 + j) * 100 + dt * 16 + lr] = cacc[dt][j];
  lds_barrier();                                     // B4
  {
    _Float16* cg = ctx + ((size_t)(b * 1024 + q0 + 16 + rq)) * 768 + h * 96 + rd0;
#pragma unroll
    for (int e = 0; e < 3; ++e) {
      float v = 0.f;
#pragma unroll
      for (int ww = 0; ww < 8; ++ww) v += ((const float*)&Pf[ww][0][0])[rq * 100 + rd0 + e];
      cg[e] = (_Float16)v;
    }
  }
}

extern "C" void kernel_launch(void* const* d_in, const int* in_sizes, int n_in,
                              void* d_out, int out_size, void* d_ws, size_t ws_size,
                              hipStream_t stream) {
  (void)in_sizes; (void)n_in; (void)out_size; (void)ws_size;
  const float* X  = (const float*)d_in[0];
  const float* Wq = (const float*)d_in[1];
  const float* bq = (const float*)d_in[2];
  const float* Wk = (const float*)d_in[3];
  const float* bk = (const float*)d_in[4];
  const float* Wv = (const float*)d_in[5];
  const float* bv = (const float*)d_in[6];
  const float* Wo = (const float*)d_in[7];
  const float* bo = (const float*)d_in[8];

  char* ws = (char*)d_ws;
  _Float16* Xh    = (_Float16*)(ws + 0);          // 16384x768 fp16      (25165824 B)
  _Float16* Wqkvt = (_Float16*)(ws + 25165824);   // 2304x768 fp16       ( 3538944 B)
  _Float16* Wot   = (_Float16*)(ws + 28704768);   // 768x768 fp16        ( 1179648 B)
  _Float16* Qh    = (_Float16*)(ws + 29884416);   // swzQ                (25165824 B)
  _Float16* Kh    = (_Float16*)(ws + 55050240);   // swzK                (25165824 B)
  _Float16* Vth   = (_Float16*)(ws + 80216064);   // swzV                (25165824 B)
  _Float16* Ctx   = (_Float16*)(ws + 105381888);  // [16384][768]        (25165824 B)

  float* out   = (float*)d_out;
  float* probs = out + 12582912;                  // [16][8][1024][1024]

  cvt_all<<<dim3(6720), dim3(256), 0, stream>>>(X, Wq, Wk, Wv, Wo, Xh, Wqkvt, Wot);
  gemm128<0, 18><<<dim3(2304), dim3(256), 0, stream>>>(Xh, Wqkvt, bq, bk, bv, Qh, Kh, Vth, nullptr);
  attn<<<dim3(4096), dim3(512), 0, stream>>>(Qh, Kh, Vth, probs, Ctx);
  gemm128<1, 6><<<dim3(768), dim3(256), 0, stream>>>(Ctx, Wot, bo, bo, bo, nullptr, nullptr, nullptr, out);
}